// Round 7
// baseline (426.612 us; speedup 1.0000x reference)
//
#include <hip/hip_runtime.h>
#include <hip/hip_bf16.h>

typedef unsigned short u16;
typedef u16 u16x8 __attribute__((ext_vector_type(8)));
typedef u16 u16x4 __attribute__((ext_vector_type(4)));
typedef __bf16 bf16x8 __attribute__((ext_vector_type(8)));
typedef float f32x4 __attribute__((ext_vector_type(4)));

__device__ __forceinline__ u16 f2bf(float f) {
  union { __hip_bfloat16 h; u16 u; } cv;
  cv.h = __float2bfloat16(f);
  return cv.u;
}
__device__ __forceinline__ float bf2f(u16 u) {
  union { unsigned u; float f; } c;
  c.u = ((unsigned)u) << 16;
  return c.f;
}

__device__ __forceinline__ void glds16(const void* g, void* l) {
  __builtin_amdgcn_global_load_lds(
      (const __attribute__((address_space(1))) unsigned int*)g,
      (__attribute__((address_space(3))) unsigned int*)l, 16, 0, 0);
}

// ---------------- transpose + fp32->bf16 convert:  W[K][N] -> Wt[N][K] ----------------
__global__ __launch_bounds__(256) void transpose_bf16(const float* __restrict__ W,
                                                      u16* __restrict__ Wt,
                                                      int K, int N) {
  __shared__ float tile[32][33];
  int tx = threadIdx.x, ty = threadIdx.y;
  int n0 = blockIdx.x * 32, k0 = blockIdx.y * 32;
#pragma unroll
  for (int j = 0; j < 4; ++j)
    tile[ty + j * 8][tx] = W[(size_t)(k0 + ty + j * 8) * N + n0 + tx];
  __syncthreads();
#pragma unroll
  for (int j = 0; j < 4; ++j)
    Wt[(size_t)(n0 + ty + j * 8) * K + k0 + tx] = f2bf(tile[tx][ty + j * 8]);
}

// four 1024x1024 transposes in one launch (z selects the weight)
__global__ __launch_bounds__(256) void transpose4(const float* __restrict__ W0,
                                                  const float* __restrict__ W1,
                                                  const float* __restrict__ W2,
                                                  const float* __restrict__ W3,
                                                  u16* __restrict__ T0, u16* __restrict__ T1,
                                                  u16* __restrict__ T2, u16* __restrict__ T3) {
  __shared__ float tile[32][33];
  int z = blockIdx.z;
  const float* W = (z == 0) ? W0 : (z == 1) ? W1 : (z == 2) ? W2 : W3;
  u16* T = (z == 0) ? T0 : (z == 1) ? T1 : (z == 2) ? T2 : T3;
  int tx = threadIdx.x, ty = threadIdx.y;
  int n0 = blockIdx.x * 32, k0 = blockIdx.y * 32;
#pragma unroll
  for (int j = 0; j < 4; ++j)
    tile[ty + j * 8][tx] = W[(size_t)(k0 + ty + j * 8) * 1024 + n0 + tx];
  __syncthreads();
#pragma unroll
  for (int j = 0; j < 4; ++j)
    T[(size_t)(n0 + ty + j * 8) * 1024 + k0 + tx] = f2bf(tile[tx][ty + j * 8]);
}

// ---------------- LayerNorm: fp32 in [rows][1024] -> bf16 out ----------------
__global__ __launch_bounds__(256) void ln_kernel(const float* __restrict__ x,
                                                 const float* __restrict__ w,
                                                 const float* __restrict__ b,
                                                 u16* __restrict__ out) {
  int row = blockIdx.x, t = threadIdx.x;
  const float* xr = x + (size_t)row * 1024;
  float4 v = *reinterpret_cast<const float4*>(xr + t * 4);
  float s = v.x + v.y + v.z + v.w;
  float s2 = v.x * v.x + v.y * v.y + v.z * v.z + v.w * v.w;
#pragma unroll
  for (int m = 1; m < 64; m <<= 1) {
    s += __shfl_xor(s, m, 64);
    s2 += __shfl_xor(s2, m, 64);
  }
  __shared__ float red[8];
  if ((t & 63) == 0) { red[t >> 6] = s; red[(t >> 6) + 4] = s2; }
  __syncthreads();
  s = red[0] + red[1] + red[2] + red[3];
  s2 = red[4] + red[5] + red[6] + red[7];
  float mu = s * (1.f / 1024.f);
  float var = s2 * (1.f / 1024.f) - mu * mu;
  float rs = rsqrtf(var + 1e-5f);
  float4 wv = *reinterpret_cast<const float4*>(w + t * 4);
  float4 bv = *reinterpret_cast<const float4*>(b + t * 4);
  u16x4 o;
  o.x = f2bf((v.x - mu) * rs * wv.x + bv.x);
  o.y = f2bf((v.y - mu) * rs * wv.y + bv.y);
  o.z = f2bf((v.z - mu) * rs * wv.z + bv.z);
  o.w = f2bf((v.w - mu) * rs * wv.w + bv.w);
  *reinterpret_cast<u16x4*>(out + (size_t)row * 1024 + t * 4) = o;
}

// ================= 256x256 MFMA GEMM, schedule v3 =================
// v2's 4-phase/1-barrier schedule + compile-time addressing: NKT templated,
// 2-tile unrolled body (buf parity compile-time), 4 global pointers advanced
// once per 2 tiles, all stage/ds_read offsets constant-folded to immediates.
// vmcnt ledger (per thread, batches of 4 loads): every staged batch drains
// exactly 3 phases after issue; final odd tile stages nothing, vmcnt(0) at p1.
// MODE 0: QKV scatter (q pre-scaled). MODE 2: bf16 gelu(acc+bias).
// MODE 3: bf16 raw partials, dst selected by zt from {o0,o1,o2,o3}.
template <int MODE, int NKT>
__global__ __launch_bounds__(512, 2) void gemm256(
    const u16* __restrict__ A, const u16* __restrict__ Bt,
    const float* __restrict__ b0, const float* __restrict__ b1,
    const float* __restrict__ b2,
    u16* __restrict__ o0, u16* __restrict__ o1, u16* __restrict__ o2,
    u16* __restrict__ o3,
    int Kfull, int MT, int NT, float qscale) {
  __shared__ u16 lds[2][2][2][256 * 32];  // [buf][op A0/B1][khalf][256r x 32c]
  const int tid = threadIdx.x;
  const int lane = tid & 63, w = tid >> 6;
  const int wm = w >> 2, wn = w & 3;
  const int l15 = lane & 15, l4 = lane >> 4;
  const int skey = (l15 >> 1) & 3;

  const int nwg = gridDim.x;
  int wg = (int)blockIdx.x;
  wg = (wg & 7) * (nwg >> 3) + (wg >> 3);
  const int mt = wg % MT;
  int rest = wg / MT;
  const int nt = rest % NT;
  const int zt = rest / NT;

  const int row0 = mt * 256, col0 = nt * 256;
  const int kbase = zt * (NKT * 64);

  // ---- precomputed global stage pointers (advance +=128 elems per 2 tiles) ----
  const int r0 = tid >> 2;
  const int sch = (tid & 3) ^ ((r0 >> 1) & 3);  // same for lo/hi chunk (128%4==0 rows)
  const u16* pA0 = A + (size_t)(row0 + r0) * Kfull + kbase + sch * 8;
  const u16* pA1 = pA0 + (size_t)128 * Kfull;
  const u16* pB0 = Bt + (size_t)(col0 + r0) * Kfull + kbase + sch * 8;
  const u16* pB1 = pB0 + (size_t)128 * Kfull;

  // ---- precomputed LDS addresses ----
  char* sb = (char*)&lds[0][0][0][0];
  u16* dA = (u16*)sb + tid * 8;            // stage dest; +buf*32768 +ks*8192 (+4096 hi)
  u16* dB = (u16*)sb + 16384 + tid * 8;
  const int aoff = ((wm * 128 + l15) * 32 + ((l4 ^ skey) << 3)) * 2;  // bytes
  const int boff = ((wn * 64 + l15) * 32 + ((l4 ^ skey) << 3)) * 2;
  const char* rbA[2] = {sb + aoff, sb + 65536 + aoff};
  const char* rbB[2] = {sb + 32768 + boff, sb + 98304 + boff};

#define RDA(BUF, KS, M) (*(const bf16x8*)(rbA[BUF] + (KS)*16384 + (M)*1024))
#define RDB(BUF, KS, N) (*(const bf16x8*)(rbB[BUF] + (KS)*16384 + (N)*1024))
#define STAGE(BUF, KS, OFFB)                                                   \
  do {                                                                         \
    glds16((const char*)pA0 + (OFFB), dA + (BUF)*32768 + (KS)*8192);           \
    glds16((const char*)pA1 + (OFFB), dA + (BUF)*32768 + (KS)*8192 + 4096);    \
    glds16((const char*)pB0 + (OFFB), dB + (BUF)*32768 + (KS)*8192);           \
    glds16((const char*)pB1 + (OFFB), dB + (BUF)*32768 + (KS)*8192 + 4096);    \
  } while (0)
#define MM1(MM, NN)                                                            \
  acc[MM][NN] = __builtin_amdgcn_mfma_f32_16x16x32_bf16(am[(MM)&3], bn[NN],    \
                                                        acc[MM][NN], 0, 0, 0)
#define MM4(MB)                                                                \
  MM1((MB)+0, 0); MM1((MB)+0, 1); MM1((MB)+0, 2); MM1((MB)+0, 3);              \
  MM1((MB)+1, 0); MM1((MB)+1, 1); MM1((MB)+1, 2); MM1((MB)+1, 3);              \
  MM1((MB)+2, 0); MM1((MB)+2, 1); MM1((MB)+2, 2); MM1((MB)+2, 3);              \
  MM1((MB)+3, 0); MM1((MB)+3, 1); MM1((MB)+3, 2); MM1((MB)+3, 3);
#define TILE(CUR, NXT, SOFF0, SOFF1, PF)                                       \
  { /* p0: ks0 mh0 */                                                          \
    am[0] = RDA(CUR, 0, 0); am[1] = RDA(CUR, 0, 1);                            \
    am[2] = RDA(CUR, 0, 2); am[3] = RDA(CUR, 0, 3);                            \
    bn[0] = RDB(CUR, 0, 0); bn[1] = RDB(CUR, 0, 1);                            \
    bn[2] = RDB(CUR, 0, 2); bn[3] = RDB(CUR, 0, 3);                            \
    if (PF) STAGE(NXT, 0, SOFF0);                                              \
    __builtin_amdgcn_s_barrier();                                              \
    __builtin_amdgcn_s_setprio(1); MM4(0) __builtin_amdgcn_s_setprio(0);       \
    /* p1: ks0 mh1 */                                                          \
    am[0] = RDA(CUR, 0, 4); am[1] = RDA(CUR, 0, 5);                            \
    am[2] = RDA(CUR, 0, 6); am[3] = RDA(CUR, 0, 7);                            \
    if (PF) { asm volatile("s_waitcnt vmcnt(4)" ::: "memory"); }               \
    else    { asm volatile("s_waitcnt vmcnt(0)" ::: "memory"); }               \
    __builtin_amdgcn_s_barrier();                                              \
    __builtin_amdgcn_s_setprio(1); MM4(4) __builtin_amdgcn_s_setprio(0);       \
    /* p2: ks1 mh0 */                                                          \
    am[0] = RDA(CUR, 1, 0); am[1] = RDA(CUR, 1, 1);                            \
    am[2] = RDA(CUR, 1, 2); am[3] = RDA(CUR, 1, 3);                            \
    bn[0] = RDB(CUR, 1, 0); bn[1] = RDB(CUR, 1, 1);                            \
    bn[2] = RDB(CUR, 1, 2); bn[3] = RDB(CUR, 1, 3);                            \
    if (PF) STAGE(NXT, 1, SOFF1);                                              \
    __builtin_amdgcn_s_barrier();                                              \
    __builtin_amdgcn_s_setprio(1); MM4(0) __builtin_amdgcn_s_setprio(0);       \
    /* p3: ks1 mh1 */                                                          \
    am[0] = RDA(CUR, 1, 4); am[1] = RDA(CUR, 1, 5);                            \
    am[2] = RDA(CUR, 1, 6); am[3] = RDA(CUR, 1, 7);                            \
    asm volatile("s_waitcnt vmcnt(4)" ::: "memory");                           \
    __builtin_amdgcn_s_barrier();                                              \
    __builtin_amdgcn_s_setprio(1); MM4(4) __builtin_amdgcn_s_setprio(0);       \
  }

  f32x4 acc[8][4];
#pragma unroll
  for (int m = 0; m < 8; ++m)
#pragma unroll
    for (int n = 0; n < 4; ++n) acc[m][n] = (f32x4){0.f, 0.f, 0.f, 0.f};

  // prologue: stage tile 0 (both k-halves); drain ks0, keep ks1 in flight
  STAGE(0, 0, 0);
  STAGE(0, 1, 64);
  asm volatile("s_waitcnt vmcnt(4)" ::: "memory");
  __builtin_amdgcn_s_barrier();

  bf16x8 am[4], bn[4];
#pragma unroll 1
  for (int it = 0; it < NKT / 2 - 1; ++it) {
    TILE(0, 1, 128, 192, true)   // even tile: compute buf0, stage T+1 -> buf1
    TILE(1, 0, 256, 320, true)   // odd tile:  compute buf1, stage T+2 -> buf0
    pA0 += 128; pA1 += 128; pB0 += 128; pB1 += 128;
  }
  TILE(0, 1, 128, 192, true)     // tile NKT-2: stage NKT-1 -> buf1
  TILE(1, 0, 0, 0, false)        // tile NKT-1: no stage; vmcnt(0) at p1

#undef RDA
#undef RDB
#undef STAGE
#undef MM1
#undef MM4
#undef TILE

  // ---------------- epilogue ----------------
  if constexpr (MODE == 0) {
    const int which = nt >> 2;   // 0=Q,1=K,2=V
    const int bidx = mt >> 2;    // batch
#pragma unroll
    for (int m = 0; m < 8; ++m)
#pragma unroll
      for (int n = 0; n < 4; ++n) {
        int colc = (col0 & 1023) + wn * 64 + n * 16 + l15;
        int hh = colc >> 6, d = colc & 63;
        int nb = (row0 & 1023) + wm * 128 + m * 16 + l4 * 4;
        if (which == 2) {
          u16x4 pk;
#pragma unroll
          for (int r = 0; r < 4; ++r) pk[r] = f2bf(acc[m][n][r] + b2[colc]);
          *reinterpret_cast<u16x4*>(o2 + (((size_t)(bidx * 16 + hh) * 64 + d) * 1024 + nb)) = pk;
        } else {
          const float* bb = (which == 0) ? b0 : b1;
          u16* dst = (which == 0) ? o0 : o1;
          float sc = (which == 0) ? qscale : 1.0f;
#pragma unroll
          for (int r = 0; r < 4; ++r)
            dst[((size_t)(bidx * 16 + hh) * 1024 + nb + r) * 64 + d] =
                f2bf((acc[m][n][r] + bb[colc]) * sc);
        }
      }
  } else if constexpr (MODE == 2) {
    const int N = NT * 256;
#pragma unroll
    for (int m = 0; m < 8; ++m)
#pragma unroll
      for (int n = 0; n < 4; ++n)
#pragma unroll
        for (int r = 0; r < 4; ++r) {
          int row = row0 + wm * 128 + m * 16 + l4 * 4 + r;
          int col = col0 + wn * 64 + n * 16 + l15;
          float val = acc[m][n][r] + b0[col];
          float g = 0.5f * val * (1.0f + erff(val * 0.70710678118f));
          o0[(size_t)row * N + col] = f2bf(g);
        }
  } else {  // MODE 3: raw bf16 partials, buffer selected by zt
    const int N = NT * 256;
    u16* base = (zt == 0) ? o0 : (zt == 1) ? o1 : (zt == 2) ? o2 : o3;
#pragma unroll
    for (int m = 0; m < 8; ++m)
#pragma unroll
      for (int n = 0; n < 4; ++n)
#pragma unroll
        for (int r = 0; r < 4; ++r) {
          int row = row0 + wm * 128 + m * 16 + l4 * 4 + r;
          int col = col0 + wn * 64 + n * 16 + l15;
          base[(size_t)row * N + col] = f2bf(acc[m][n][r]);
        }
  }
}

// ---------------- split-K reduce: out = p0+p1+p2+p3 + bias + res (N=1024 cols) -------
__global__ __launch_bounds__(256) void reduce4(const u16* __restrict__ p0,
                                               const u16* __restrict__ p1,
                                               const u16* __restrict__ p2,
                                               const u16* __restrict__ p3,
                                               const float* __restrict__ bias,
                                               const float* __restrict__ res,
                                               float* __restrict__ out) {
  size_t i = ((size_t)blockIdx.x * 256 + threadIdx.x) * 8;
  int col = (int)(i & 1023);
  float s[8];
  float4 r0 = *reinterpret_cast<const float4*>(res + i);
  float4 r1 = *reinterpret_cast<const float4*>(res + i + 4);
  s[0] = r0.x; s[1] = r0.y; s[2] = r0.z; s[3] = r0.w;
  s[4] = r1.x; s[5] = r1.y; s[6] = r1.z; s[7] = r1.w;
#pragma unroll
  for (int j = 0; j < 8; ++j) s[j] += bias[col + j];
  const u16* ps[4] = {p0, p1, p2, p3};
#pragma unroll
  for (int sp = 0; sp < 4; ++sp) {
    u16x8 pv = *reinterpret_cast<const u16x8*>(ps[sp] + i);
#pragma unroll
    for (int j = 0; j < 8; ++j) s[j] += bf2f(pv[j]);
  }
  float4 o0 = {s[0], s[1], s[2], s[3]};
  float4 o1 = {s[4], s[5], s[6], s[7]};
  *reinterpret_cast<float4*>(out + i) = o0;
  *reinterpret_cast<float4*>(out + i + 4) = o1;
}

// ---------------- fused flash attention, swapped-operand softmax ----------------
// q,k: [BH, N, 64] bf16 (q pre-scaled by 0.125*log2e); vt: [BH, 64, N] bf16
// S^T = mfma(K,Q): each lane owns one q-row -> lane-local softmax (2 shuffles).
// O^T = mfma(V^T, P^T). out o: [B, N, 1024] bf16.
__global__ __launch_bounds__(256) void attn_kernel(const u16* __restrict__ q,
                                                   const u16* __restrict__ k,
                                                   const u16* __restrict__ vt,
                                                   u16* __restrict__ o) {
  const int bh = blockIdx.x, qb = blockIdx.y;
  const int b = bh >> 4, h = bh & 15;
  __shared__ u16 Ks[2][4096];
  __shared__ u16 Vt[2][4096];
  __shared__ u16 Ps[4][1024];
  const int tid = threadIdx.x, lane = tid & 63, w = tid >> 6;
  const int l15 = lane & 15, l4 = lane >> 4;
  const int sw = l15 & 7;
  const u16* kbase = k + (size_t)bh * 65536;
  const u16* vtbase = vt + (size_t)bh * 65536;

  // Q B-fragment straight from global: Q[q=w*16+l15][kd=l4*8..]
  const u16* qrow = q + ((size_t)bh * 1024 + qb * 64 + w * 16 + l15) * 64;
  bf16x8 qf0 = *reinterpret_cast<const bf16x8*>(qrow + l4 * 8);
  bf16x8 qf1 = *reinterpret_cast<const bf16x8*>(qrow + 32 + l4 * 8);

  auto stageKV = [&](int buf, int kv0) {
#pragma unroll
    for (int i = 0; i < 2; ++i) {
      int c = i * 256 + tid, r = c >> 3, sl = (c & 7) ^ (r & 7);
      glds16(kbase + (size_t)(kv0 + r) * 64 + sl * 8, &Ks[buf][c * 8]);
    }
#pragma unroll
    for (int i = 0; i < 2; ++i) {
      int c = i * 256 + tid, r = c >> 3, sl = (c & 7) ^ (r & 7);
      glds16(vtbase + (size_t)r * 1024 + kv0 + sl * 8, &Vt[buf][c * 8]);
    }
  };

  f32x4 oacc[4];  // O^T: oacc[n][r] = O^T[d = n*16 + l4*4 + r][q = w*16+l15]
#pragma unroll
  for (int n = 0; n < 4; ++n) oacc[n] = (f32x4){0.f, 0.f, 0.f, 0.f};
  float mrow = -3.0e38f, lrow = 0.f;  // per-lane scalars (one q-row per lane)

  stageKV(0, 0);
  __syncthreads();

  for (int kv0 = 0; kv0 < 1024; kv0 += 64) {
    int cur = (kv0 >> 6) & 1;
    if (kv0 + 64 < 1024) stageKV(cur ^ 1, kv0 + 64);

    // S^T[k][q]: st[t][r] = S[k = t*16 + l4*4 + r][q = l15]
    f32x4 st[4];
#pragma unroll
    for (int t = 0; t < 4; ++t) {
      int row = t * 16 + l15;
      f32x4 s = (f32x4){0.f, 0.f, 0.f, 0.f};
      bf16x8 kf0 = *reinterpret_cast<const bf16x8*>(&Ks[cur][row * 64 + ((l4 ^ sw) << 3)]);
      s = __builtin_amdgcn_mfma_f32_16x16x32_bf16(kf0, qf0, s, 0, 0, 0);
      bf16x8 kf1 = *reinterpret_cast<const bf16x8*>(&Ks[cur][row * 64 + (((4 + l4) ^ sw) << 3)]);
      s = __builtin_amdgcn_mfma_f32_16x16x32_bf16(kf1, qf1, s, 0, 0, 0);
      st[t] = s;
    }

    // lane-local softmax over the 16 values + 2 shuffles (lanes l15+{0,16,32,48})
    float tm = st[0][0];
#pragma unroll
    for (int t = 0; t < 4; ++t)
#pragma unroll
      for (int r = 0; r < 4; ++r) tm = fmaxf(tm, st[t][r]);
    tm = fmaxf(tm, __shfl_xor(tm, 16, 64));
    tm = fmaxf(tm, __shfl_xor(tm, 32, 64));
    if (!__all(tm - mrow <= 8.f)) {  // defer-max (T13): skip rescale when growth small
      float mnew = fmaxf(mrow, tm);
      float al = exp2f(mrow - mnew);
      lrow *= al;
#pragma unroll
      for (int n = 0; n < 4; ++n)
#pragma unroll
        for (int r = 0; r < 4; ++r) oacc[n][r] *= al;
      mrow = mnew;
    }
    float pr[4][4];
    float ps = 0.f;
#pragma unroll
    for (int t = 0; t < 4; ++t)
#pragma unroll
      for (int r = 0; r < 4; ++r) {
        pr[t][r] = exp2f(st[t][r] - mrow);
        ps += pr[t][r];
      }
    ps += __shfl_xor(ps, 16, 64);
    ps += __shfl_xor(ps, 32, 64);
    lrow += ps;

    // pack P: row q=l15, k-run of 4 at k0 = t*16 + l4*4 -> one b64 write per t
#pragma unroll
    for (int t = 0; t < 4; ++t) {
      u16x4 pk;
#pragma unroll
      for (int r = 0; r < 4; ++r) pk[r] = f2bf(pr[t][r]);
      int swch = ((t << 1) | (l4 >> 1)) ^ sw;
      *reinterpret_cast<u16x4*>(&Ps[w][l15 * 64 + swch * 8 + (l4 & 1) * 4]) = pk;
    }

    // O^T += V^T * P^T
#pragma unroll
    for (int c2 = 0; c2 < 2; ++c2) {
      bf16x8 pf = *reinterpret_cast<const bf16x8*>(
          &Ps[w][l15 * 64 + ((((c2 << 2) | l4) ^ sw) << 3)]);
#pragma unroll
      for (int n = 0; n < 4; ++n) {
        bf16x8 vf = *reinterpret_cast<const bf16x8*>(
            &Vt[cur][(n * 16 + l15) * 64 + ((((c2 << 2) | l4) ^ sw) << 3)]);
        oacc[n] = __builtin_amdgcn_mfma_f32_16x16x32_bf16(vf, pf, oacc[n], 0, 0, 0);
      }
    }
    __syncthreads();
  }

  float inv = 1.0f / lrow;
  int nr = qb * 64 + w * 16 + l15;
#pragma unroll
  for (int n = 0; n < 4; ++n) {
    u16x4 pk;
#pragma unroll
    for (int r = 0; r < 4; ++r) pk[r] = f2bf(oacc[n][r] * inv);
    *reinterpret_cast<u16x4*>(
        o + ((size_t)(b * 1024 + nr)) * 1024 + h * 64 + n * 16 + l4 * 4) = pk;
  }
}

extern "C" void kernel_launch(void* const* d_in, const int* in_sizes, int n_in,
                              void* d_out, int out_size, void* d_ws, size_t ws_size,
                              hipStream_t stream) {
  (void)in_sizes; (void)n_in; (void)out_size; (void)ws_size;
  const float* x     = (const float*)d_in[0];
  const float* ln1w  = (const float*)d_in[1];
  const float* ln1b  = (const float*)d_in[2];
  const float* Wq    = (const float*)d_in[3];
  const float* bq    = (const float*)d_in[4];
  const float* Wk    = (const float*)d_in[5];
  const float* bk    = (const float*)d_in[6];
  const float* Wv    = (const float*)d_in[7];
  const float* bv    = (const float*)d_in[8];
  const float* Wo    = (const float*)d_in[9];
  const float* bo    = (const float*)d_in[10];
  const float* ln2w  = (const float*)d_in[11];
  const float* ln2b  = (const float*)d_in[12];
  const float* Wfc   = (const float*)d_in[13];
  const float* bfc   = (const float*)d_in[14];
  const float* Wproj = (const float*)d_in[15];
  const float* bproj = (const float*)d_in[16];
  float* out = (float*)d_out;

  char* p = (char*)d_ws;
  u16* hb     = (u16*)p; p += (size_t)4096 * 1024 * 2;   // LN1 out bf16
  u16* WqkvT  = (u16*)p; p += (size_t)3072 * 1024 * 2;
  u16* WoT    = (u16*)p; p += (size_t)1024 * 1024 * 2;
  u16* WfcT   = (u16*)p; p += (size_t)4096 * 1024 * 2;
  u16* WprojT = (u16*)p; p += (size_t)1024 * 4096 * 2;
  u16* qb_    = (u16*)p; p += (size_t)4096 * 1024 * 2;   // q; also split-K partial 0
  u16* kb_    = (u16*)p; p += (size_t)4096 * 1024 * 2;   // k; partial 1
  u16* vt_    = (u16*)p; p += (size_t)4096 * 1024 * 2;   // V^T; partial 2
  u16* ob_    = (u16*)p; p += (size_t)4096 * 1024 * 2;   // attn out; Proj partial 3
  float* x1   = (float*)p; p += (size_t)4096 * 1024 * 4; // residual 1 fp32
  u16* h2     = (u16*)p; p += (size_t)4096 * 1024 * 2;   // Wo partial 3; then LN2 out
  u16* ffnb   = (u16*)p; p += (size_t)4096 * 4096 * 2;   // gelu out bf16

  const float qscale = 0.125f * 1.44269504089f;  // 1/sqrt(64) * log2(e)

  dim3 tb(32, 8);
  transpose4<<<dim3(32, 32, 4), tb, 0, stream>>>(Wq, Wk, Wv, Wo,
                                                 WqkvT, WqkvT + (size_t)1024 * 1024,
                                                 WqkvT + (size_t)2048 * 1024, WoT);
  transpose_bf16<<<dim3(128, 32), tb, 0, stream>>>(Wfc, WfcT, 1024, 4096);
  transpose_bf16<<<dim3(32, 128), tb, 0, stream>>>(Wproj, WprojT, 4096, 1024);

  ln_kernel<<<4096, 256, 0, stream>>>(x, ln1w, ln1b, hb);

  // QKV: M=4096, N=3072, K=1024 -> 16x12 = 192 blocks, NKT=16
  gemm256<0, 16><<<192, 512, 0, stream>>>(hb, WqkvT, bq, bk, bv,
                                          qb_, kb_, vt_, nullptr, 1024, 16, 12, qscale);

  attn_kernel<<<dim3(64, 16), 256, 0, stream>>>(qb_, kb_, vt_, ob_);

  // Wo: M=4096, N=1024, K=1024, split-K=4 (NKT=4) -> 256 blocks; partials qb_,kb_,vt_,h2
  gemm256<3, 4><<<256, 512, 0, stream>>>(ob_, WoT, nullptr, nullptr, nullptr,
                                         qb_, kb_, vt_, h2, 1024, 16, 4, 1.f);
  reduce4<<<2048, 256, 0, stream>>>(qb_, kb_, vt_, h2, bo, x, x1);

  ln_kernel<<<4096, 256, 0, stream>>>(x1, ln2w, ln2b, h2);

  // FC: M=4096, N=4096, K=1024 -> 256 blocks, NKT=16
  gemm256<2, 16><<<256, 512, 0, stream>>>(h2, WfcT, bfc, nullptr, nullptr,
                                          ffnb, nullptr, nullptr, nullptr, 1024, 16, 16, 1.f);

  // Proj: M=4096, N=1024, K=4096, split-K=4 (NKT=16) -> 256 blocks; partials qb_..ob_
  gemm256<3, 16><<<256, 512, 0, stream>>>(ffnb, WprojT, nullptr, nullptr, nullptr,
                                          qb_, kb_, vt_, ob_, 4096, 16, 4, 1.f);
  reduce4<<<2048, 256, 0, stream>>>(qb_, kb_, vt_, ob_, bproj, x1, out);
}

// Round 8
// 339.622 us; speedup vs baseline: 1.2561x; 1.2561x over previous
//
#include <hip/hip_runtime.h>
#include <hip/hip_bf16.h>

typedef unsigned short u16;
typedef u16 u16x8 __attribute__((ext_vector_type(8)));
typedef u16 u16x4 __attribute__((ext_vector_type(4)));
typedef __bf16 bf16x8 __attribute__((ext_vector_type(8)));
typedef float f32x4 __attribute__((ext_vector_type(4)));

__device__ __forceinline__ u16 f2bf(float f) {
  union { __hip_bfloat16 h; u16 u; } cv;
  cv.h = __float2bfloat16(f);
  return cv.u;
}
__device__ __forceinline__ float bf2f(u16 u) {
  union { unsigned u; float f; } c;
  c.u = ((unsigned)u) << 16;
  return c.f;
}

__device__ __forceinline__ void glds16(const void* g, void* l) {
  __builtin_amdgcn_global_load_lds(
      (const __attribute__((address_space(1))) unsigned int*)g,
      (__attribute__((address_space(3))) unsigned int*)l, 16, 0, 0);
}

// ---------------- transpose + fp32->bf16 convert:  W[K][N] -> Wt[N][K] ----------------
__global__ __launch_bounds__(256) void transpose_bf16(const float* __restrict__ W,
                                                      u16* __restrict__ Wt,
                                                      int K, int N) {
  __shared__ float tile[32][33];
  int tx = threadIdx.x, ty = threadIdx.y;
  int n0 = blockIdx.x * 32, k0 = blockIdx.y * 32;
#pragma unroll
  for (int j = 0; j < 4; ++j)
    tile[ty + j * 8][tx] = W[(size_t)(k0 + ty + j * 8) * N + n0 + tx];
  __syncthreads();
#pragma unroll
  for (int j = 0; j < 4; ++j)
    Wt[(size_t)(n0 + ty + j * 8) * K + k0 + tx] = f2bf(tile[tx][ty + j * 8]);
}

// four 1024x1024 transposes in one launch (z selects the weight)
__global__ __launch_bounds__(256) void transpose4(const float* __restrict__ W0,
                                                  const float* __restrict__ W1,
                                                  const float* __restrict__ W2,
                                                  const float* __restrict__ W3,
                                                  u16* __restrict__ T0, u16* __restrict__ T1,
                                                  u16* __restrict__ T2, u16* __restrict__ T3) {
  __shared__ float tile[32][33];
  int z = blockIdx.z;
  const float* W = (z == 0) ? W0 : (z == 1) ? W1 : (z == 2) ? W2 : W3;
  u16* T = (z == 0) ? T0 : (z == 1) ? T1 : (z == 2) ? T2 : T3;
  int tx = threadIdx.x, ty = threadIdx.y;
  int n0 = blockIdx.x * 32, k0 = blockIdx.y * 32;
#pragma unroll
  for (int j = 0; j < 4; ++j)
    tile[ty + j * 8][tx] = W[(size_t)(k0 + ty + j * 8) * 1024 + n0 + tx];
  __syncthreads();
#pragma unroll
  for (int j = 0; j < 4; ++j)
    T[(size_t)(n0 + ty + j * 8) * 1024 + k0 + tx] = f2bf(tile[tx][ty + j * 8]);
}

// ---------------- LayerNorm: fp32 in [rows][1024] -> bf16 out ----------------
__global__ __launch_bounds__(256) void ln_kernel(const float* __restrict__ x,
                                                 const float* __restrict__ w,
                                                 const float* __restrict__ b,
                                                 u16* __restrict__ out) {
  int row = blockIdx.x, t = threadIdx.x;
  const float* xr = x + (size_t)row * 1024;
  float4 v = *reinterpret_cast<const float4*>(xr + t * 4);
  float s = v.x + v.y + v.z + v.w;
  float s2 = v.x * v.x + v.y * v.y + v.z * v.z + v.w * v.w;
#pragma unroll
  for (int m = 1; m < 64; m <<= 1) {
    s += __shfl_xor(s, m, 64);
    s2 += __shfl_xor(s2, m, 64);
  }
  __shared__ float red[8];
  if ((t & 63) == 0) { red[t >> 6] = s; red[(t >> 6) + 4] = s2; }
  __syncthreads();
  s = red[0] + red[1] + red[2] + red[3];
  s2 = red[4] + red[5] + red[6] + red[7];
  float mu = s * (1.f / 1024.f);
  float var = s2 * (1.f / 1024.f) - mu * mu;
  float rs = rsqrtf(var + 1e-5f);
  float4 wv = *reinterpret_cast<const float4*>(w + t * 4);
  float4 bv = *reinterpret_cast<const float4*>(b + t * 4);
  u16x4 o;
  o.x = f2bf((v.x - mu) * rs * wv.x + bv.x);
  o.y = f2bf((v.y - mu) * rs * wv.y + bv.y);
  o.z = f2bf((v.z - mu) * rs * wv.z + bv.z);
  o.w = f2bf((v.w - mu) * rs * wv.w + bv.w);
  *reinterpret_cast<u16x4*>(out + (size_t)row * 1024 + t * 4) = o;
}

// ================= 256x256 MFMA GEMM, schedule v2 (round-6 proven) =================
// 4 phases per K-tile(64), split by m-half x k-half; ONE barrier per phase
// (pre-MFMA). Stage {A,B} of one k-half at p0/p2 into the non-live buffer;
// vmcnt(4) at p1/p3 -> every drain waits on loads issued 3 phases earlier.
// MODE 0: QKV scatter (q pre-scaled). MODE 2: bf16 gelu(acc+bias).
// MODE 3: bf16 raw partials, dst selected by zt from {o0,o1,o2,o3}.
template <int MODE>
__global__ __launch_bounds__(512, 2) void gemm256(
    const u16* __restrict__ A, const u16* __restrict__ Bt,
    const float* __restrict__ b0, const float* __restrict__ b1,
    const float* __restrict__ b2,
    u16* __restrict__ o0, u16* __restrict__ o1, u16* __restrict__ o2,
    u16* __restrict__ o3,
    int Kfull, int KL, int MT, int NT, float qscale) {
  __shared__ u16 lds[2][2][2][256 * 32];  // [buf][op A0/B1][khalf][256 rows x 32 cols]
  const int tid = threadIdx.x;
  const int lane = tid & 63, w = tid >> 6;
  const int wm = w >> 2, wn = w & 3;
  const int l15 = lane & 15, l4 = lane >> 4;
  const int skey = (l15 >> 1) & 3;

  const int nwg = gridDim.x;
  int wg = (int)blockIdx.x;
  wg = (wg & 7) * (nwg >> 3) + (wg >> 3);
  const int mt = wg % MT;
  int rest = wg / MT;
  const int nt = rest % NT;
  const int zt = rest / NT;

  const int row0 = mt * 256, col0 = nt * 256;
  const int kbase = zt * KL;
  const int nkt = KL >> 6;

  // stage both A and B of one k-half (4 glds16 per thread = one vmcnt unit)
  auto stageAB = [&](int buf, int ks, int kt) {
    const int kb = kbase + (kt << 6) + (ks << 5);
#pragma unroll
    for (int i = 0; i < 2; ++i) {
      int c = i * 512 + tid;
      int r = c >> 2, sch = (c & 3) ^ ((r >> 1) & 3);
      glds16(A + (size_t)(row0 + r) * Kfull + kb + sch * 8, &lds[buf][0][ks][0] + c * 8);
    }
#pragma unroll
    for (int i = 0; i < 2; ++i) {
      int c = i * 512 + tid;
      int r = c >> 2, sch = (c & 3) ^ ((r >> 1) & 3);
      glds16(Bt + (size_t)(col0 + r) * Kfull + kb + sch * 8, &lds[buf][1][ks][0] + c * 8);
    }
  };
  auto rdA = [&](int buf, int ks, int m) -> bf16x8 {
    int row = wm * 128 + m * 16 + l15;
    return *reinterpret_cast<const bf16x8*>(&lds[buf][0][ks][row * 32 + ((l4 ^ skey) << 3)]);
  };
  auto rdB = [&](int buf, int ks, int n) -> bf16x8 {
    int row = wn * 64 + n * 16 + l15;
    return *reinterpret_cast<const bf16x8*>(&lds[buf][1][ks][row * 32 + ((l4 ^ skey) << 3)]);
  };

  f32x4 acc[8][4];
#pragma unroll
  for (int m = 0; m < 8; ++m)
#pragma unroll
    for (int n = 0; n < 4; ++n) acc[m][n] = (f32x4){0.f, 0.f, 0.f, 0.f};

  // prologue: stage tile 0 fully; drain the ks0 batch, keep ks1 in flight
  stageAB(0, 0, 0);
  stageAB(0, 1, 0);
  asm volatile("s_waitcnt vmcnt(4)" ::: "memory");
  __builtin_amdgcn_s_barrier();

  bf16x8 am[4], bn[4];
  for (int t = 0; t < nkt; ++t) {
    const int cur = t & 1, nxt = cur ^ 1;
    const bool pf = (t + 1 < nkt);
    // ---- p0: ks0, m-half 0 ----
    {
#pragma unroll
      for (int m = 0; m < 4; ++m) am[m] = rdA(cur, 0, m);
#pragma unroll
      for (int n = 0; n < 4; ++n) bn[n] = rdB(cur, 0, n);
      if (pf) stageAB(nxt, 0, t + 1);
      __builtin_amdgcn_s_barrier();
      __builtin_amdgcn_s_setprio(1);
#pragma unroll
      for (int m = 0; m < 4; ++m)
#pragma unroll
        for (int n = 0; n < 4; ++n)
          acc[m][n] = __builtin_amdgcn_mfma_f32_16x16x32_bf16(am[m], bn[n], acc[m][n], 0, 0, 0);
      __builtin_amdgcn_s_setprio(0);
    }
    // ---- p1: ks0, m-half 1 ----
    {
#pragma unroll
      for (int m = 0; m < 4; ++m) am[m] = rdA(cur, 0, m + 4);
      if (pf) {
        asm volatile("s_waitcnt vmcnt(4)" ::: "memory");
      } else {
        asm volatile("s_waitcnt vmcnt(0)" ::: "memory");
      }
      __builtin_amdgcn_s_barrier();
      __builtin_amdgcn_s_setprio(1);
#pragma unroll
      for (int m = 0; m < 4; ++m)
#pragma unroll
        for (int n = 0; n < 4; ++n)
          acc[m + 4][n] = __builtin_amdgcn_mfma_f32_16x16x32_bf16(am[m], bn[n], acc[m + 4][n], 0, 0, 0);
      __builtin_amdgcn_s_setprio(0);
    }
    // ---- p2: ks1, m-half 0 ----
    {
#pragma unroll
      for (int m = 0; m < 4; ++m) am[m] = rdA(cur, 1, m);
#pragma unroll
      for (int n = 0; n < 4; ++n) bn[n] = rdB(cur, 1, n);
      if (pf) stageAB(nxt, 1, t + 1);
      __builtin_amdgcn_s_barrier();
      __builtin_amdgcn_s_setprio(1);
#pragma unroll
      for (int m = 0; m < 4; ++m)
#pragma unroll
        for (int n = 0; n < 4; ++n)
          acc[m][n] = __builtin_amdgcn_mfma_f32_16x16x32_bf16(am[m], bn[n], acc[m][n], 0, 0, 0);
      __builtin_amdgcn_s_setprio(0);
    }
    // ---- p3: ks1, m-half 1 ----
    {
#pragma unroll
      for (int m = 0; m < 4; ++m) am[m] = rdA(cur, 1, m + 4);
      asm volatile("s_waitcnt vmcnt(4)" ::: "memory");
      __builtin_amdgcn_s_barrier();
      __builtin_amdgcn_s_setprio(1);
#pragma unroll
      for (int m = 0; m < 4; ++m)
#pragma unroll
        for (int n = 0; n < 4; ++n)
          acc[m + 4][n] = __builtin_amdgcn_mfma_f32_16x16x32_bf16(am[m], bn[n], acc[m + 4][n], 0, 0, 0);
      __builtin_amdgcn_s_setprio(0);
    }
  }

  // ---------------- epilogue ----------------
  if constexpr (MODE == 0) {
    const int which = nt >> 2;   // 0=Q,1=K,2=V
    const int bidx = mt >> 2;    // batch
#pragma unroll
    for (int m = 0; m < 8; ++m)
#pragma unroll
      for (int n = 0; n < 4; ++n) {
        int colc = (col0 & 1023) + wn * 64 + n * 16 + l15;
        int hh = colc >> 6, d = colc & 63;
        int nb = (row0 & 1023) + wm * 128 + m * 16 + l4 * 4;
        if (which == 2) {
          u16x4 pk;
#pragma unroll
          for (int r = 0; r < 4; ++r) pk[r] = f2bf(acc[m][n][r] + b2[colc]);
          *reinterpret_cast<u16x4*>(o2 + (((size_t)(bidx * 16 + hh) * 64 + d) * 1024 + nb)) = pk;
        } else {
          const float* bb = (which == 0) ? b0 : b1;
          u16* dst = (which == 0) ? o0 : o1;
          float sc = (which == 0) ? qscale : 1.0f;
#pragma unroll
          for (int r = 0; r < 4; ++r)
            dst[((size_t)(bidx * 16 + hh) * 1024 + nb + r) * 64 + d] =
                f2bf((acc[m][n][r] + bb[colc]) * sc);
        }
      }
  } else if constexpr (MODE == 2) {
    const int N = NT * 256;
#pragma unroll
    for (int m = 0; m < 8; ++m)
#pragma unroll
      for (int n = 0; n < 4; ++n)
#pragma unroll
        for (int r = 0; r < 4; ++r) {
          int row = row0 + wm * 128 + m * 16 + l4 * 4 + r;
          int col = col0 + wn * 64 + n * 16 + l15;
          float val = acc[m][n][r] + b0[col];
          float g = 0.5f * val * (1.0f + erff(val * 0.70710678118f));
          o0[(size_t)row * N + col] = f2bf(g);
        }
  } else {  // MODE 3: raw bf16 partials, buffer selected by zt
    const int N = NT * 256;
    u16* base = (zt == 0) ? o0 : (zt == 1) ? o1 : (zt == 2) ? o2 : o3;
#pragma unroll
    for (int m = 0; m < 8; ++m)
#pragma unroll
      for (int n = 0; n < 4; ++n)
#pragma unroll
        for (int r = 0; r < 4; ++r) {
          int row = row0 + wm * 128 + m * 16 + l4 * 4 + r;
          int col = col0 + wn * 64 + n * 16 + l15;
          base[(size_t)row * N + col] = f2bf(acc[m][n][r]);
        }
  }
}

// ---------------- split-K reduce: out = p0+p1+p2+p3 + bias + res (N=1024 cols) -------
__global__ __launch_bounds__(256) void reduce4(const u16* __restrict__ p0,
                                               const u16* __restrict__ p1,
                                               const u16* __restrict__ p2,
                                               const u16* __restrict__ p3,
                                               const float* __restrict__ bias,
                                               const float* __restrict__ res,
                                               float* __restrict__ out) {
  size_t i = ((size_t)blockIdx.x * 256 + threadIdx.x) * 8;
  int col = (int)(i & 1023);
  float s[8];
  float4 r0 = *reinterpret_cast<const float4*>(res + i);
  float4 r1 = *reinterpret_cast<const float4*>(res + i + 4);
  s[0] = r0.x; s[1] = r0.y; s[2] = r0.z; s[3] = r0.w;
  s[4] = r1.x; s[5] = r1.y; s[6] = r1.z; s[7] = r1.w;
#pragma unroll
  for (int j = 0; j < 8; ++j) s[j] += bias[col + j];
  const u16* ps[4] = {p0, p1, p2, p3};
#pragma unroll
  for (int sp = 0; sp < 4; ++sp) {
    u16x8 pv = *reinterpret_cast<const u16x8*>(ps[sp] + i);
#pragma unroll
    for (int j = 0; j < 8; ++j) s[j] += bf2f(pv[j]);
  }
  float4 o0 = {s[0], s[1], s[2], s[3]};
  float4 o1 = {s[4], s[5], s[6], s[7]};
  *reinterpret_cast<float4*>(out + i) = o0;
  *reinterpret_cast<float4*>(out + i + 4) = o1;
}

// ---- fused split-K reduce + LayerNorm: x1 = p0..p3 + bias + res; h2 = LN(x1) ----
// one block per row (1024 cols, 256 threads x 4)
__global__ __launch_bounds__(256) void reduce_ln(const u16* __restrict__ p0,
                                                 const u16* __restrict__ p1,
                                                 const u16* __restrict__ p2,
                                                 const u16* __restrict__ p3,
                                                 const float* __restrict__ bias,
                                                 const float* __restrict__ res,
                                                 const float* __restrict__ lnw,
                                                 const float* __restrict__ lnb,
                                                 float* __restrict__ x1,
                                                 u16* __restrict__ h2out) {
  int row = blockIdx.x, t = threadIdx.x;
  size_t i = (size_t)row * 1024 + t * 4;
  int col = t * 4;
  float4 r = *reinterpret_cast<const float4*>(res + i);
  float4 bi = *reinterpret_cast<const float4*>(bias + col);
  float v0 = r.x + bi.x, v1 = r.y + bi.y, v2 = r.z + bi.z, v3 = r.w + bi.w;
  const u16* ps[4] = {p0, p1, p2, p3};
#pragma unroll
  for (int sp = 0; sp < 4; ++sp) {
    u16x4 pv = *reinterpret_cast<const u16x4*>(ps[sp] + i);
    v0 += bf2f(pv[0]); v1 += bf2f(pv[1]); v2 += bf2f(pv[2]); v3 += bf2f(pv[3]);
  }
  float4 xo = {v0, v1, v2, v3};
  *reinterpret_cast<float4*>(x1 + i) = xo;

  float s = v0 + v1 + v2 + v3;
  float s2 = v0 * v0 + v1 * v1 + v2 * v2 + v3 * v3;
#pragma unroll
  for (int m = 1; m < 64; m <<= 1) {
    s += __shfl_xor(s, m, 64);
    s2 += __shfl_xor(s2, m, 64);
  }
  __shared__ float red[8];
  if ((t & 63) == 0) { red[t >> 6] = s; red[(t >> 6) + 4] = s2; }
  __syncthreads();
  s = red[0] + red[1] + red[2] + red[3];
  s2 = red[4] + red[5] + red[6] + red[7];
  float mu = s * (1.f / 1024.f);
  float var = s2 * (1.f / 1024.f) - mu * mu;
  float rs = rsqrtf(var + 1e-5f);
  float4 wv = *reinterpret_cast<const float4*>(lnw + col);
  float4 bv = *reinterpret_cast<const float4*>(lnb + col);
  u16x4 o;
  o.x = f2bf((v0 - mu) * rs * wv.x + bv.x);
  o.y = f2bf((v1 - mu) * rs * wv.y + bv.y);
  o.z = f2bf((v2 - mu) * rs * wv.z + bv.z);
  o.w = f2bf((v3 - mu) * rs * wv.w + bv.w);
  *reinterpret_cast<u16x4*>(h2out + i) = o;
}

// ---------------- fused flash attention, swapped-operand softmax ----------------
// q,k: [BH, N, 64] bf16 (q pre-scaled by 0.125*log2e); vt: [BH, 64, N] bf16
// S^T = mfma(K,Q): each lane owns one q-row -> lane-local softmax (2 shuffles).
// O^T = mfma(V^T, P^T). out o: [B, N, 1024] bf16.
__global__ __launch_bounds__(256) void attn_kernel(const u16* __restrict__ q,
                                                   const u16* __restrict__ k,
                                                   const u16* __restrict__ vt,
                                                   u16* __restrict__ o) {
  const int bh = blockIdx.x, qb = blockIdx.y;
  const int b = bh >> 4, h = bh & 15;
  __shared__ u16 Ks[2][4096];
  __shared__ u16 Vt[2][4096];
  __shared__ u16 Ps[4][1024];
  const int tid = threadIdx.x, lane = tid & 63, w = tid >> 6;
  const int l15 = lane & 15, l4 = lane >> 4;
  const int sw = l15 & 7;
  const u16* kbase = k + (size_t)bh * 65536;
  const u16* vtbase = vt + (size_t)bh * 65536;

  // Q B-fragment straight from global: Q[q=w*16+l15][kd=l4*8..]
  const u16* qrow = q + ((size_t)bh * 1024 + qb * 64 + w * 16 + l15) * 64;
  bf16x8 qf0 = *reinterpret_cast<const bf16x8*>(qrow + l4 * 8);
  bf16x8 qf1 = *reinterpret_cast<const bf16x8*>(qrow + 32 + l4 * 8);

  auto stageKV = [&](int buf, int kv0) {
#pragma unroll
    for (int i = 0; i < 2; ++i) {
      int c = i * 256 + tid, r = c >> 3, sl = (c & 7) ^ (r & 7);
      glds16(kbase + (size_t)(kv0 + r) * 64 + sl * 8, &Ks[buf][c * 8]);
    }
#pragma unroll
    for (int i = 0; i < 2; ++i) {
      int c = i * 256 + tid, r = c >> 3, sl = (c & 7) ^ (r & 7);
      glds16(vtbase + (size_t)r * 1024 + kv0 + sl * 8, &Vt[buf][c * 8]);
    }
  };

  f32x4 oacc[4];  // O^T: oacc[n][r] = O^T[d = n*16 + l4*4 + r][q = w*16+l15]
#pragma unroll
  for (int n = 0; n < 4; ++n) oacc[n] = (f32x4){0.f, 0.f, 0.f, 0.f};
  float mrow = -3.0e38f, lrow = 0.f;  // per-lane scalars (one q-row per lane)

  stageKV(0, 0);
  __syncthreads();

  for (int kv0 = 0; kv0 < 1024; kv0 += 64) {
    int cur = (kv0 >> 6) & 1;
    if (kv0 + 64 < 1024) stageKV(cur ^ 1, kv0 + 64);

    // S^T[k][q]: st[t][r] = S[k = t*16 + l4*4 + r][q = l15]
    f32x4 st[4];
#pragma unroll
    for (int t = 0; t < 4; ++t) {
      int row = t * 16 + l15;
      f32x4 s = (f32x4){0.f, 0.f, 0.f, 0.f};
      bf16x8 kf0 = *reinterpret_cast<const bf16x8*>(&Ks[cur][row * 64 + ((l4 ^ sw) << 3)]);
      s = __builtin_amdgcn_mfma_f32_16x16x32_bf16(kf0, qf0, s, 0, 0, 0);
      bf16x8 kf1 = *reinterpret_cast<const bf16x8*>(&Ks[cur][row * 64 + (((4 + l4) ^ sw) << 3)]);
      s = __builtin_amdgcn_mfma_f32_16x16x32_bf16(kf1, qf1, s, 0, 0, 0);
      st[t] = s;
    }

    // lane-local softmax over the 16 values + 2 shuffles (lanes l15+{0,16,32,48})
    float tm = st[0][0];
#pragma unroll
    for (int t = 0; t < 4; ++t)
#pragma unroll
      for (int r = 0; r < 4; ++r) tm = fmaxf(tm, st[t][r]);
    tm = fmaxf(tm, __shfl_xor(tm, 16, 64));
    tm = fmaxf(tm, __shfl_xor(tm, 32, 64));
    if (!__all(tm - mrow <= 8.f)) {  // defer-max (T13): skip rescale when growth small
      float mnew = fmaxf(mrow, tm);
      float al = exp2f(mrow - mnew);
      lrow *= al;
#pragma unroll
      for (int n = 0; n < 4; ++n)
#pragma unroll
        for (int r = 0; r < 4; ++r) oacc[n][r] *= al;
      mrow = mnew;
    }
    float pr[4][4];
    float ps = 0.f;
#pragma unroll
    for (int t = 0; t < 4; ++t)
#pragma unroll
      for (int r = 0; r < 4; ++r) {
        pr[t][r] = exp2f(st[t][r] - mrow);
        ps += pr[t][r];
      }
    ps += __shfl_xor(ps, 16, 64);
    ps += __shfl_xor(ps, 32, 64);
    lrow += ps;

    // pack P: row q=l15, k-run of 4 at k0 = t*16 + l4*4 -> one b64 write per t
#pragma unroll
    for (int t = 0; t < 4; ++t) {
      u16x4 pk;
#pragma unroll
      for (int r = 0; r < 4; ++r) pk[r] = f2bf(pr[t][r]);
      int swch = ((t << 1) | (l4 >> 1)) ^ sw;
      *reinterpret_cast<u16x4*>(&Ps[w][l15 * 64 + swch * 8 + (l4 & 1) * 4]) = pk;
    }

    // O^T += V^T * P^T
#pragma unroll
    for (int c2 = 0; c2 < 2; ++c2) {
      bf16x8 pf = *reinterpret_cast<const bf16x8*>(
          &Ps[w][l15 * 64 + ((((c2 << 2) | l4) ^ sw) << 3)]);
#pragma unroll
      for (int n = 0; n < 4; ++n) {
        bf16x8 vf = *reinterpret_cast<const bf16x8*>(
            &Vt[cur][(n * 16 + l15) * 64 + ((((c2 << 2) | l4) ^ sw) << 3)]);
        oacc[n] = __builtin_amdgcn_mfma_f32_16x16x32_bf16(vf, pf, oacc[n], 0, 0, 0);
      }
    }
    __syncthreads();
  }

  float inv = 1.0f / lrow;
  int nr = qb * 64 + w * 16 + l15;
#pragma unroll
  for (int n = 0; n < 4; ++n) {
    u16x4 pk;
#pragma unroll
    for (int r = 0; r < 4; ++r) pk[r] = f2bf(oacc[n][r] * inv);
    *reinterpret_cast<u16x4*>(
        o + ((size_t)(b * 1024 + nr)) * 1024 + h * 64 + n * 16 + l4 * 4) = pk;
  }
}

extern "C" void kernel_launch(void* const* d_in, const int* in_sizes, int n_in,
                              void* d_out, int out_size, void* d_ws, size_t ws_size,
                              hipStream_t stream) {
  (void)in_sizes; (void)n_in; (void)out_size; (void)ws_size;
  const float* x     = (const float*)d_in[0];
  const float* ln1w  = (const float*)d_in[1];
  const float* ln1b  = (const float*)d_in[2];
  const float* Wq    = (const float*)d_in[3];
  const float* bq    = (const float*)d_in[4];
  const float* Wk    = (const float*)d_in[5];
  const float* bk    = (const float*)d_in[6];
  const float* Wv    = (const float*)d_in[7];
  const float* bv    = (const float*)d_in[8];
  const float* Wo    = (const float*)d_in[9];
  const float* bo    = (const float*)d_in[10];
  const float* ln2w  = (const float*)d_in[11];
  const float* ln2b  = (const float*)d_in[12];
  const float* Wfc   = (const float*)d_in[13];
  const float* bfc   = (const float*)d_in[14];
  const float* Wproj = (const float*)d_in[15];
  const float* bproj = (const float*)d_in[16];
  float* out = (float*)d_out;

  char* p = (char*)d_ws;
  u16* hb     = (u16*)p; p += (size_t)4096 * 1024 * 2;   // LN1 out; later LN2 out
  u16* WqkvT  = (u16*)p; p += (size_t)3072 * 1024 * 2;
  u16* WoT    = (u16*)p; p += (size_t)1024 * 1024 * 2;
  u16* WfcT   = (u16*)p; p += (size_t)4096 * 1024 * 2;
  u16* WprojT = (u16*)p; p += (size_t)1024 * 4096 * 2;
  u16* qb_    = (u16*)p; p += (size_t)4096 * 1024 * 2;   // q; also split-K partial 0
  u16* kb_    = (u16*)p; p += (size_t)4096 * 1024 * 2;   // k; partial 1
  u16* vt_    = (u16*)p; p += (size_t)4096 * 1024 * 2;   // V^T; partial 2
  u16* ob_    = (u16*)p; p += (size_t)4096 * 1024 * 2;   // attn out; Proj partial 3
  float* x1   = (float*)p; p += (size_t)4096 * 1024 * 4; // residual 1 fp32
  u16* h2     = (u16*)p; p += (size_t)4096 * 1024 * 2;   // Wo partial 3
  u16* ffnb   = (u16*)p; p += (size_t)4096 * 4096 * 2;   // gelu out bf16

  const float qscale = 0.125f * 1.44269504089f;  // 1/sqrt(64) * log2(e)

  dim3 tb(32, 8);
  transpose4<<<dim3(32, 32, 4), tb, 0, stream>>>(Wq, Wk, Wv, Wo,
                                                 WqkvT, WqkvT + (size_t)1024 * 1024,
                                                 WqkvT + (size_t)2048 * 1024, WoT);
  transpose_bf16<<<dim3(128, 32), tb, 0, stream>>>(Wfc, WfcT, 1024, 4096);
  transpose_bf16<<<dim3(32, 128), tb, 0, stream>>>(Wproj, WprojT, 4096, 1024);

  ln_kernel<<<4096, 256, 0, stream>>>(x, ln1w, ln1b, hb);

  // QKV: M=4096, N=3072, K=1024 -> 16x12 = 192 blocks
  gemm256<0><<<192, 512, 0, stream>>>(hb, WqkvT, bq, bk, bv,
                                      qb_, kb_, vt_, nullptr, 1024, 1024, 16, 12, qscale);

  attn_kernel<<<dim3(64, 16), 256, 0, stream>>>(qb_, kb_, vt_, ob_);

  // Wo: M=4096, N=1024, K=1024, split-K=4 (KL=256) -> 256 blocks; partials qb_,kb_,vt_,h2
  gemm256<3><<<256, 512, 0, stream>>>(ob_, WoT, nullptr, nullptr, nullptr,
                                      qb_, kb_, vt_, h2, 1024, 256, 16, 4, 1.f);
  // fused: x1 = partials + bo + x; hb = LN2(x1)
  reduce_ln<<<4096, 256, 0, stream>>>(qb_, kb_, vt_, h2, bo, x, ln2w, ln2b, x1, hb);

  // FC: M=4096, N=4096, K=1024 -> 256 blocks
  gemm256<2><<<256, 512, 0, stream>>>(hb, WfcT, bfc, nullptr, nullptr,
                                      ffnb, nullptr, nullptr, nullptr, 1024, 1024, 16, 16, 1.f);

  // Proj: M=4096, N=1024, K=4096, split-K=4 (KL=1024) -> 256 blocks; partials qb_..ob_
  gemm256<3><<<256, 512, 0, stream>>>(ffnb, WprojT, nullptr, nullptr, nullptr,
                                      qb_, kb_, vt_, ob_, 4096, 1024, 16, 4, 1.f);
  reduce4<<<2048, 256, 0, stream>>>(qb_, kb_, vt_, ob_, bproj, x1, out);
}